// Round 2
// baseline (266.434 us; speedup 1.0000x reference)
//
#include <hip/hip_runtime.h>
#include <hip/hip_bf16.h>

// Problem constants: features [B=32, D=1024, M=512] fp32.
#define B_ 32
#define D_ 1024
#define M_ 512
#define OUTROW 524800  // D*(D+1)/2
#define ALPHA_ 0.4f
#define EPS_ 1e-5f

typedef __bf16 bf16x8 __attribute__((ext_vector_type(8)));
typedef float f32x4 __attribute__((ext_vector_type(4)));

// ---------------------------------------------------------------------------
// Kernel A: cast features fp32->bf16 + diag[b,d] = sum_m f^2 / (2M) (fp32).
// One wave per row (512 elems), 4 rows per 256-thread block.
// Also zeroes rowsum/totals (folded memset: saves a dispatch).
// ---------------------------------------------------------------------------
__global__ __launch_bounds__(256) void prep_kernel(
    const float* __restrict__ feat, __bf16* __restrict__ featbf,
    float* __restrict__ diag, float* __restrict__ rowsum,
    float* __restrict__ totals)
{
    // folded accumulator zeroing: 128 blocks x 256 threads = 32768 = B*D
    if (blockIdx.x < 128) {
        rowsum[blockIdx.x * 256 + threadIdx.x] = 0.0f;
        if (blockIdx.x == 0 && threadIdx.x < B_) totals[threadIdx.x] = 0.0f;
    }

    const int w = threadIdx.x >> 6, l = threadIdx.x & 63;
    const int row = blockIdx.x * 4 + w;          // 0 .. 32767
    const float4* fp = (const float4*)(feat + (size_t)row * M_);
    float4 v0 = fp[l * 2];
    float4 v1 = fp[l * 2 + 1];
    bf16x8 h;
    h[0] = (__bf16)v0.x; h[1] = (__bf16)v0.y; h[2] = (__bf16)v0.z; h[3] = (__bf16)v0.w;
    h[4] = (__bf16)v1.x; h[5] = (__bf16)v1.y; h[6] = (__bf16)v1.z; h[7] = (__bf16)v1.w;
    *(bf16x8*)(featbf + (size_t)row * M_ + l * 8) = h;
    float s = v0.x*v0.x + v0.y*v0.y + v0.z*v0.z + v0.w*v0.w
            + v1.x*v1.x + v1.y*v1.y + v1.z*v1.z + v1.w*v1.w;
    #pragma unroll
    for (int off = 32; off; off >>= 1) s += __shfl_down(s, off);
    if (l == 0) diag[row] = s * (1.0f / (2.0f * M_));
}

// ---------------------------------------------------------------------------
// Kernel B: Gram + fused dcov->pow epilogue. NEW STRUCTURE: 64x64 tile per
// WAVE, MFMA fragments loaded DIRECTLY from global (L2-resident panels) into
// registers -- no LDS, no barriers, 4352 fully independent self-paced waves.
// Register double-buffer gives a 1-deep prefetch; one k-step of MFMA covers
// L2 latency. Fragment loads are perfectly coalesced (16 rows x 64B / instr).
// ---------------------------------------------------------------------------
#define LOADFR(AB, BB, K)                                                    \
    { _Pragma("unroll")                                                      \
      for (int f = 0; f < 4; ++f) {                                          \
          AB[f] = *(const bf16x8*)(pa + (size_t)f * (16 * M_) + (K) * 32);   \
          BB[f] = *(const bf16x8*)(pb + (size_t)f * (16 * M_) + (K) * 32);   \
      } }

#define MFMAS(AB, BB)                                                        \
    { _Pragma("unroll")                                                      \
      for (int mi = 0; mi < 4; ++mi) {                                       \
          _Pragma("unroll")                                                  \
          for (int nj = 0; nj < 4; ++nj)                                     \
              acc[mi][nj] = __builtin_amdgcn_mfma_f32_16x16x32_bf16(         \
                  AB[mi], BB[nj], acc[mi][nj], 0, 0, 0);                     \
      } }

__global__ __launch_bounds__(256) void gram_kernel(
    const __bf16* __restrict__ feat, const float* __restrict__ diag,
    float* __restrict__ out, float* __restrict__ rowsum,
    float* __restrict__ totals)
{
    const int t = threadIdx.x;
    const int w = t >> 6, l = t & 63;
    const int quad = l >> 4, l15 = l & 15;

    // XCD-aware decode: each XCD owns 4 batches {xcd, xcd+8, xcd+16, xcd+24}
    // processed sequentially -> per-XCD L2 holds the active feature panels.
    // Each block's 4 waves take 4 consecutive 64x64 triangular tiles.
    const int L = blockIdx.x;                // 0..1087
    const int xcd = L & 7;
    const int slot = L >> 3;                 // 0..135
    const int b = xcd + 8 * (slot / 34);
    const int tile = (slot % 34) * 4 + w;    // 0..135 (136 tiles/batch)
    int u = tile, ti = 0;
    while (u >= 16 - ti) { u -= 16 - ti; ti++; }
    const int tj = ti + u;
    const bool diagTile = (ti == tj);

    const __bf16* Ab = feat + (size_t)b * (D_ * M_) + (size_t)ti * 64 * M_;
    const __bf16* Bb = feat + (size_t)b * (D_ * M_) + (size_t)tj * 64 * M_;

    // Per-lane fragment base: row = f*16 + l15 (stride M_), k-chunk = quad*8.
    const __bf16* pa = Ab + (size_t)l15 * M_ + quad * 8;
    const __bf16* pb = Bb + (size_t)l15 * M_ + quad * 8;

    f32x4 acc[4][4] = {};
    bf16x8 a0[4], b0[4], a1[4], b1[4];

    LOADFR(a0, b0, 0);
    #pragma unroll
    for (int kk = 0; kk < 8; ++kk) {
        LOADFR(a1, b1, 2 * kk + 1);          // prefetch odd step
        MFMAS(a0, b0);                       // compute even step
        if (kk < 7) LOADFR(a0, b0, 2 * kk + 2);  // prefetch next even
        MFMAS(a1, b1);                       // compute odd step
    }

    // ---------------- epilogue (unchanged math) ----------------
    const int gi0 = ti * 64;
    const int gj0 = tj * 64;
    const float* diagB = diag + b * D_;
    float di[4][4], dj[4];
    #pragma unroll
    for (int mi = 0; mi < 4; ++mi)
        #pragma unroll
        for (int r = 0; r < 4; ++r)
            di[mi][r] = diagB[gi0 + mi * 16 + quad * 4 + r];
    #pragma unroll
    for (int nj = 0; nj < 4; ++nj)
        dj[nj] = diagB[gj0 + nj * 16 + l15];

    float* outB = out + (size_t)b * OUTROW;
    float rs[4][4] = {};
    float cs[4] = {};
    float wt = 0.f;
    const float invK = 1.0f / 512.0f;  // dcov = di + dj - dot/512

    #pragma unroll
    for (int mi = 0; mi < 4; ++mi) {
        #pragma unroll
        for (int nj = 0; nj < 4; ++nj) {
            const f32x4 a = acc[mi][nj];
            const int j = gj0 + nj * 16 + l15;
            #pragma unroll
            for (int r = 0; r < 4; ++r) {
                const int i = gi0 + mi * 16 + quad * 4 + r;
                float d = di[mi][r] + dj[nj] - a[r] * invK;
                if (i == j) d = 0.0f;   // exact: ref has dcov(i,i) == 0
                d = fmaxf(d, 0.0f);
                const float p = __builtin_exp2f(ALPHA_ * __builtin_log2f(d + EPS_));
                rs[mi][r] += p;
                cs[nj] += p;
                wt += p;
                if (!diagTile || j >= i)
                    outB[(size_t)i * D_ - ((size_t)i * (i + 1)) / 2 + j] = p;
            }
        }
    }

    // row-sum contributions: reduce across l15 lanes
    #pragma unroll
    for (int mi = 0; mi < 4; ++mi) {
        #pragma unroll
        for (int r = 0; r < 4; ++r) {
            float v = rs[mi][r];
            v += __shfl_xor(v, 1); v += __shfl_xor(v, 2);
            v += __shfl_xor(v, 4); v += __shfl_xor(v, 8);
            if (l15 == 0)
                unsafeAtomicAdd(&rowsum[b * D_ + gi0 + mi * 16 + quad * 4 + r], v);
        }
    }
    // col-sum contributions map to rowsum[j] by symmetry (off-diag tiles only)
    if (!diagTile) {
        #pragma unroll
        for (int nj = 0; nj < 4; ++nj) {
            float v = cs[nj];
            v += __shfl_xor(v, 16); v += __shfl_xor(v, 32);
            if (quad == 0)
                unsafeAtomicAdd(&rowsum[b * D_ + gj0 + nj * 16 + l15], v);
        }
    }
    // batch total (off-diag tiles counted twice: tile + mirror)
    float v = wt;
    #pragma unroll
    for (int off = 32; off; off >>= 1) v += __shfl_down(v, off);
    if (l == 0) unsafeAtomicAdd(&totals[b], diagTile ? v : 2.0f * v);
}

// ---------------------------------------------------------------------------
// Kernel C: in-place double-centering. Row-paired for load balance: block x
// handles rows x and D-1-x (combined length D+1, uniform across blocks).
// Plain cached loads/stores (NT regressed: partial-line write-through).
// ---------------------------------------------------------------------------
__global__ __launch_bounds__(256) void center_kernel(
    float* __restrict__ out, const float* __restrict__ rowsum,
    const float* __restrict__ totals)
{
    const int b = blockIdx.y;
    const float* rsB = rowsum + b * D_;
    const float tm = totals[b] * (1.0f / ((float)D_ * (float)D_));
    #pragma unroll
    for (int h = 0; h < 2; ++h) {
        const int i = h ? (D_ - 1 - (int)blockIdx.x) : (int)blockIdx.x;
        const float rmi = rsB[i] * (1.0f / D_);
        float* row = out + (size_t)b * OUTROW + (size_t)i * D_ - ((size_t)i * (i + 1)) / 2;
        for (int j = i + (int)threadIdx.x; j < D_; j += 256) {
            row[j] = row[j] - rmi - rsB[j] * (1.0f / D_) + tm;
        }
    }
}

// ---------------------------------------------------------------------------
extern "C" void kernel_launch(void* const* d_in, const int* in_sizes, int n_in,
                              void* d_out, int out_size, void* d_ws, size_t ws_size,
                              hipStream_t stream) {
    const float* feat = (const float*)d_in[0];
    float* out = (float*)d_out;

    char* ws = (char*)d_ws;
    __bf16* featbf = (__bf16*)ws;                            // 33,554,432 B
    float* diag    = (float*)(ws + 33554432);                //    131,072 B
    float* rowsum  = (float*)(ws + 33554432 + 131072);       //    131,072 B
    float* totals  = (float*)(ws + 33554432 + 262144);       //        128 B

    // rowsum/totals zeroing folded into prep_kernel (stream-ordered before gram)
    prep_kernel<<<dim3((B_ * D_) / 4), dim3(256), 0, stream>>>(feat, featbf, diag,
                                                               rowsum, totals);
    gram_kernel<<<dim3(8 * 136), dim3(256), 0, stream>>>(featbf, diag, out, rowsum, totals);
    center_kernel<<<dim3(D_ / 2, B_), dim3(256), 0, stream>>>(out, rowsum, totals);
}

// Round 3
// 203.733 us; speedup vs baseline: 1.3078x; 1.3078x over previous
//
#include <hip/hip_runtime.h>
#include <hip/hip_bf16.h>

// Problem constants: features [B=32, D=1024, M=512] fp32.
#define B_ 32
#define D_ 1024
#define M_ 512
#define OUTROW 524800  // D*(D+1)/2
#define ALPHA_ 0.4f
#define EPS_ 1e-5f

typedef __bf16 bf16x8 __attribute__((ext_vector_type(8)));
typedef float f32x4 __attribute__((ext_vector_type(4)));

// ---------------------------------------------------------------------------
// Kernel A: cast features fp32->bf16 + diag[b,d] = sum_m f^2 / (2M) (fp32).
// One wave per row (512 elems), 4 rows per 256-thread block.
// Also zeroes rowsum/totals (folded memset: saves a dispatch).
// ---------------------------------------------------------------------------
__global__ __launch_bounds__(256) void prep_kernel(
    const float* __restrict__ feat, __bf16* __restrict__ featbf,
    float* __restrict__ diag, float* __restrict__ rowsum,
    float* __restrict__ totals)
{
    // folded accumulator zeroing: 128 blocks x 256 threads = 32768 = B*D
    if (blockIdx.x < 128) {
        rowsum[blockIdx.x * 256 + threadIdx.x] = 0.0f;
        if (blockIdx.x == 0 && threadIdx.x < B_) totals[threadIdx.x] = 0.0f;
    }

    const int w = threadIdx.x >> 6, l = threadIdx.x & 63;
    const int row = blockIdx.x * 4 + w;          // 0 .. 32767
    const float4* fp = (const float4*)(feat + (size_t)row * M_);
    float4 v0 = fp[l * 2];
    float4 v1 = fp[l * 2 + 1];
    bf16x8 h;
    h[0] = (__bf16)v0.x; h[1] = (__bf16)v0.y; h[2] = (__bf16)v0.z; h[3] = (__bf16)v0.w;
    h[4] = (__bf16)v1.x; h[5] = (__bf16)v1.y; h[6] = (__bf16)v1.z; h[7] = (__bf16)v1.w;
    *(bf16x8*)(featbf + (size_t)row * M_ + l * 8) = h;
    float s = v0.x*v0.x + v0.y*v0.y + v0.z*v0.z + v0.w*v0.w
            + v1.x*v1.x + v1.y*v1.y + v1.z*v1.z + v1.w*v1.w;
    #pragma unroll
    for (int off = 32; off; off >>= 1) s += __shfl_down(s, off);
    if (l == 0) diag[row] = s * (1.0f / (2.0f * M_));
}

// ---------------------------------------------------------------------------
// Kernel B: upper-triangular-tile Gram GEMM (bf16 MFMA 16x16x32), fused
// dcov -> pow epilogue, XCD-batch-swizzled. Tile 128x128, 4 waves.
// Round-1 structure (best measured: 91.8 us): BK=32, depth-2 prefetch into
// 3 LDS buffers, raw s_barrier + counted s_waitcnt vmcnt(4), 2-way-free LDS
// swizzle, setprio around MFMA cluster. Plain (cached) out stores so the
// 67MB out stays L3-resident for the centering pass.
// ---------------------------------------------------------------------------
__global__ __launch_bounds__(256, 3) void gram_kernel(
    const __bf16* __restrict__ feat, const float* __restrict__ diag,
    float* __restrict__ out, float* __restrict__ rowsum,
    float* __restrict__ totals)
{
    // [stage%3][slot] ; slot = row*4 + swizzled-chunk, 16B per slot
    __shared__ __bf16 As[3][512 * 8];
    __shared__ __bf16 Bs[3][512 * 8];

    const int t = threadIdx.x;
    const int w = t >> 6, l = t & 63;
    const int quad = l >> 4, l15 = l & 15;

    // XCD-aware decode: linear id -> (xcd, slot); each XCD owns batches
    // {xcd, xcd+8, xcd+16, xcd+24} processed sequentially -> per-XCD L2 reuse.
    const int L = blockIdx.x;
    const int xcd = L & 7;
    const int slot = L >> 3;                 // 0..143
    const int b = xcd + 8 * (slot / 36);
    int u = slot % 36, ti = 0;
    while (u >= 8 - ti) { u -= 8 - ti; ti++; }
    const int tj = ti + u;
    const bool diagTile = (ti == tj);

    const __bf16* Ab = feat + (size_t)b * (D_ * M_) + (size_t)ti * 128 * M_;
    const __bf16* Bb = feat + (size_t)b * (D_ * M_) + (size_t)tj * 128 * M_;

    const int wm = w >> 1, wn = w & 1;

    // Preload diag fragments now: global-load latency hides under the K-loop.
    const int gi0 = ti * 128 + wm * 64;
    const int gj0 = tj * 128 + wn * 64;
    const float* diagB = diag + b * D_;
    float di[4][4], dj[4];
    #pragma unroll
    for (int mi = 0; mi < 4; ++mi)
        #pragma unroll
        for (int r = 0; r < 4; ++r)
            di[mi][r] = diagB[gi0 + mi * 16 + quad * 4 + r];
    #pragma unroll
    for (int nj = 0; nj < 4; ++nj)
        dj[nj] = diagB[gj0 + nj * 16 + l15];

    f32x4 acc[4][4] = {};

    // stage s: load A/B rows [0,128) cols [s*32, s*32+32) into buffer sb.
    // LDS dest is linear per wave (global_load_lds requirement); the bank
    // swizzle is applied on the per-lane GLOBAL source address (m173 pattern).
    auto stage = [&](int s, int sb) {
        const int koff = s * 32;
        #pragma unroll
        for (int it = 0; it < 2; ++it) {
            const int idx = it * 256 + t;          // slot 0..511
            const int row = idx >> 2;              // 0..127
            const int cg = (idx & 3) ^ ((row >> 1) & 3);  // swizzled chunk-of-8
            const __bf16* ga = Ab + row * M_ + koff + cg * 8;
            const __bf16* gb = Bb + row * M_ + koff + cg * 8;
            __builtin_amdgcn_global_load_lds(
                (const __attribute__((address_space(1))) void*)ga,
                (__attribute__((address_space(3))) void*)(&As[sb][(it * 256 + w * 64) * 8]),
                16, 0, 0);
            __builtin_amdgcn_global_load_lds(
                (const __attribute__((address_space(1))) void*)gb,
                (__attribute__((address_space(3))) void*)(&Bs[sb][(it * 256 + w * 64) * 8]),
                16, 0, 0);
        }
    };

    stage(0, 0);          // 4 loads/thread in flight
    stage(1, 1);          // 8 in flight
    int rb = 0, sn = 2;   // read buffer, next stage buffer
    for (int k0 = 0; k0 < 16; ++k0) {
        // Counted wait: own buffer-k0 loads (oldest 4) complete; the 4
        // prefetch loads for k0+1 stay in flight across the barrier.
        if (k0 < 15) asm volatile("s_waitcnt vmcnt(4)" ::: "memory");
        else         asm volatile("s_waitcnt vmcnt(0)" ::: "memory");
        __builtin_amdgcn_s_barrier();
        __builtin_amdgcn_sched_barrier(0);   // pin: nothing moves above barrier
        if (k0 + 2 < 16) stage(k0 + 2, sn);  // depth-2 prefetch

        bf16x8 af[4], bfr[4];
        #pragma unroll
        for (int mi = 0; mi < 4; ++mi) {
            const int row = wm * 64 + mi * 16 + l15;
            af[mi] = *(const bf16x8*)(&As[rb][(row * 4 + (quad ^ ((row >> 1) & 3))) * 8]);
        }
        #pragma unroll
        for (int nj = 0; nj < 4; ++nj) {
            const int row = wn * 64 + nj * 16 + l15;
            bfr[nj] = *(const bf16x8*)(&Bs[rb][(row * 4 + (quad ^ ((row >> 1) & 3))) * 8]);
        }
        __builtin_amdgcn_s_setprio(1);
        #pragma unroll
        for (int mi = 0; mi < 4; ++mi)
            #pragma unroll
            for (int nj = 0; nj < 4; ++nj)
                acc[mi][nj] = __builtin_amdgcn_mfma_f32_16x16x32_bf16(
                    af[mi], bfr[nj], acc[mi][nj], 0, 0, 0);
        __builtin_amdgcn_s_setprio(0);
        rb = (rb == 2) ? 0 : rb + 1;
        sn = (sn == 2) ? 0 : sn + 1;
    }

    // ---------------- epilogue ----------------
    float* outB = out + (size_t)b * OUTROW;
    float rs[4][4] = {};
    float cs[4] = {};
    float wt = 0.f;
    const float invK = 1.0f / 512.0f;  // dcov = di + dj - dot/512

    #pragma unroll
    for (int mi = 0; mi < 4; ++mi) {
        #pragma unroll
        for (int nj = 0; nj < 4; ++nj) {
            const f32x4 a = acc[mi][nj];
            const int j = gj0 + nj * 16 + l15;
            #pragma unroll
            for (int r = 0; r < 4; ++r) {
                const int i = gi0 + mi * 16 + quad * 4 + r;
                float d = di[mi][r] + dj[nj] - a[r] * invK;
                if (i == j) d = 0.0f;   // exact: ref has dcov(i,i) == 0
                d = fmaxf(d, 0.0f);
                const float p = __builtin_exp2f(ALPHA_ * __builtin_log2f(d + EPS_));
                rs[mi][r] += p;
                cs[nj] += p;
                wt += p;
                if (!diagTile || j >= i)
                    outB[(size_t)i * D_ - ((size_t)i * (i + 1)) / 2 + j] = p;
            }
        }
    }

    // row-sum contributions: reduce across l15 lanes
    #pragma unroll
    for (int mi = 0; mi < 4; ++mi) {
        #pragma unroll
        for (int r = 0; r < 4; ++r) {
            float v = rs[mi][r];
            v += __shfl_xor(v, 1); v += __shfl_xor(v, 2);
            v += __shfl_xor(v, 4); v += __shfl_xor(v, 8);
            if (l15 == 0)
                unsafeAtomicAdd(&rowsum[b * D_ + gi0 + mi * 16 + quad * 4 + r], v);
        }
    }
    // col-sum contributions map to rowsum[j] by symmetry (off-diag tiles only)
    if (!diagTile) {
        #pragma unroll
        for (int nj = 0; nj < 4; ++nj) {
            float v = cs[nj];
            v += __shfl_xor(v, 16); v += __shfl_xor(v, 32);
            if (quad == 0)
                unsafeAtomicAdd(&rowsum[b * D_ + gj0 + nj * 16 + l15], v);
        }
    }
    // batch total (off-diag tiles counted twice: tile + mirror)
    float v = wt;
    #pragma unroll
    for (int off = 32; off; off >>= 1) v += __shfl_down(v, off);
    if (l == 0) unsafeAtomicAdd(&totals[b], diagTile ? v : 2.0f * v);
}

// ---------------------------------------------------------------------------
// Kernel C: in-place double-centering, LINEAR float4 pass over the packed
// triangle (fully coalesced 16B/lane RMW, grid-stride, 2048 blocks).
// Row i recovered from flat index e via closed-form sqrt + integer fixup:
//   start(i) = i*(2D+1-i)/2 ;  i = floor((2D+1 - sqrt((2D+1)^2 - 8e)) / 2)
// ---------------------------------------------------------------------------
__global__ __launch_bounds__(256) void center_kernel(
    float* __restrict__ out, const float* __restrict__ rowsum,
    const float* __restrict__ totals)
{
    const int tot4 = OUTROW / 4;             // 131200 float4s per batch
    const float invD = 1.0f / (float)D_;
    const int gsz = gridDim.x * 256;

    for (int g = blockIdx.x * 256 + threadIdx.x; g < B_ * tot4; g += gsz) {
        const int b = g / tot4;              // magic-mul (constant divisor)
        const int e = (g - b * tot4) * 4;    // element index in packed triangle
        const float* rsB = rowsum + b * D_;
        const float tm = totals[b] * (1.0f / ((float)D_ * (float)D_));
        float* outB = out + (size_t)b * OUTROW;

        // row from flat index (D=1024: (2D+1)^2 = 2049^2 = 4198401)
        const float disc = 4198401.0f - 8.0f * (float)e;
        int i = (int)((2049.0f - __builtin_sqrtf(disc)) * 0.5f);
        if (i > 1023) i = 1023;
        if (i < 0) i = 0;
        // integer fixup for approx-sqrt boundary error (start(1024)=OUTROW sentinel)
        while (i * (2049 - i) / 2 > e) --i;
        while ((i + 1) * (2049 - (i + 1)) / 2 <= e) ++i;

        float4 v = *(float4*)(outB + e);
        float r[4] = {v.x, v.y, v.z, v.w};
        int ii = i;
        int si = ii * (2049 - ii) / 2;            // start(ii)
        int sn = (ii + 1) * (2049 - ii - 1) / 2;  // start(ii+1)
        #pragma unroll
        for (int q = 0; q < 4; ++q) {
            const int eq = e + q;
            while (eq >= sn) {                    // row crossing (short rows)
                ++ii; si = sn;
                sn = (ii + 1) * (2049 - ii - 1) / 2;
            }
            const int j = eq - si + ii;
            r[q] = r[q] - (rsB[ii] + rsB[j]) * invD + tm;
        }
        v.x = r[0]; v.y = r[1]; v.z = r[2]; v.w = r[3];
        *(float4*)(outB + e) = v;
    }
}

// ---------------------------------------------------------------------------
extern "C" void kernel_launch(void* const* d_in, const int* in_sizes, int n_in,
                              void* d_out, int out_size, void* d_ws, size_t ws_size,
                              hipStream_t stream) {
    const float* feat = (const float*)d_in[0];
    float* out = (float*)d_out;

    char* ws = (char*)d_ws;
    __bf16* featbf = (__bf16*)ws;                            // 33,554,432 B
    float* diag    = (float*)(ws + 33554432);                //    131,072 B
    float* rowsum  = (float*)(ws + 33554432 + 131072);       //    131,072 B
    float* totals  = (float*)(ws + 33554432 + 262144);       //        128 B

    // rowsum/totals zeroing folded into prep_kernel (stream-ordered before gram)
    prep_kernel<<<dim3((B_ * D_) / 4), dim3(256), 0, stream>>>(feat, featbf, diag,
                                                               rowsum, totals);
    gram_kernel<<<dim3(36 * B_), dim3(256), 0, stream>>>(featbf, diag, out, rowsum, totals);
    center_kernel<<<dim3(2048), dim3(256), 0, stream>>>(out, rowsum, totals);
}